// Round 1
// baseline (812.218 us; speedup 1.0000x reference)
//
#include <hip/hip_runtime.h>

#define Bn 4
#define Sn 1024
#define En 1024
#define Wn 768
#define Hn 12
#define Dn 64

// ---------------------------------------------------------------------------
// Kernel 1: fused QKV projection.  C[M=4096, N=2304] = X[:, :768] @ W^T + b
// Tile 128x128, BK=8, 256 threads, 8x8 micro-tile per thread.
// Writes q/k/v in [B,H,S,D] layout into workspace.
// ---------------------------------------------------------------------------
__global__ __launch_bounds__(256) void qkv_kernel(
    const float* __restrict__ x,
    const float* __restrict__ qw, const float* __restrict__ qb,
    const float* __restrict__ kw, const float* __restrict__ kb,
    const float* __restrict__ vw, const float* __restrict__ vb,
    float* __restrict__ qo, float* __restrict__ ko, float* __restrict__ vo)
{
    __shared__ __align__(16) float As[8][132];
    __shared__ __align__(16) float Bs[8][132];
    const int tid = threadIdx.x;
    const int m0 = blockIdx.x * 128;
    const int ng = blockIdx.y * 128;          // global n in [0, 2304)
    const int which = ng / Wn;                // 0=q, 1=k, 2=v (tile never straddles)
    const int n0 = ng - which * Wn;           // within-matrix feature base
    const float* wp = (which == 0) ? qw : (which == 1) ? kw : vw;
    const float* bp = (which == 0) ? qb : (which == 1) ? kb : vb;
    float*       op = (which == 0) ? qo : (which == 1) ? ko : vo;

    const int lr = tid >> 1;                  // load row 0..127
    const int lc = (tid & 1) * 4;             // load col 0 or 4
    const int tr = (tid >> 4) * 8;            // micro-tile row base
    const int tc = (tid & 15) * 8;            // micro-tile col base

    float acc[8][8];
    #pragma unroll
    for (int i = 0; i < 8; ++i)
        #pragma unroll
        for (int j = 0; j < 8; ++j) acc[i][j] = 0.f;

    for (int k0 = 0; k0 < Wn; k0 += 8) {
        float4 av = *(const float4*)(x  + (size_t)(m0 + lr) * En + k0 + lc);
        float4 bv = *(const float4*)(wp + (size_t)(n0 + lr) * En + k0 + lc);
        __syncthreads();
        As[lc + 0][lr] = av.x; As[lc + 1][lr] = av.y;
        As[lc + 2][lr] = av.z; As[lc + 3][lr] = av.w;
        Bs[lc + 0][lr] = bv.x; Bs[lc + 1][lr] = bv.y;
        Bs[lc + 2][lr] = bv.z; Bs[lc + 3][lr] = bv.w;
        __syncthreads();
        #pragma unroll
        for (int kk = 0; kk < 8; ++kk) {
            float a[8], bb[8];
            *(float4*)&a[0]  = *(const float4*)&As[kk][tr];
            *(float4*)&a[4]  = *(const float4*)&As[kk][tr + 4];
            *(float4*)&bb[0] = *(const float4*)&Bs[kk][tc];
            *(float4*)&bb[4] = *(const float4*)&Bs[kk][tc + 4];
            #pragma unroll
            for (int i = 0; i < 8; ++i)
                #pragma unroll
                for (int j = 0; j < 8; ++j)
                    acc[i][j] += a[i] * bb[j];
        }
    }

    // epilogue: bias + scatter into [B,H,S,D]
    const int np = n0 + tc;                   // within-matrix feature, mult of 8
    const int h  = np >> 6;                   // head (uniform across j)
    const int d0 = np & 63;                   // head-dim base (8-aligned)
    float bias[8];
    #pragma unroll
    for (int j = 0; j < 8; ++j) bias[j] = bp[np + j];

    #pragma unroll
    for (int i = 0; i < 8; ++i) {
        const int m = m0 + tr + i;
        const int b = m >> 10;
        const int s = m & 1023;
        float* dst = op + (((size_t)b * Hn + h) * Sn + s) * Dn + d0;
        float4 v0 = make_float4(acc[i][0] + bias[0], acc[i][1] + bias[1],
                                acc[i][2] + bias[2], acc[i][3] + bias[3]);
        float4 v1 = make_float4(acc[i][4] + bias[4], acc[i][5] + bias[5],
                                acc[i][6] + bias[6], acc[i][7] + bias[7]);
        *(float4*)(dst)     = v0;
        *(float4*)(dst + 4) = v1;
    }
}

// ---------------------------------------------------------------------------
// Kernel 2: attention. One block = one (b, h, 64-row q-tile).
// Pass A: sum of exp over keys (no max-subtract; scores bounded, masked -> 0,
// matching exp(-1e9 - m) -> 0 in the reference).
// Pass B: recompute scores, write normalized weights to d_out, accumulate P@V.
// ---------------------------------------------------------------------------
__global__ __launch_bounds__(256) void attn_kernel(
    const float* __restrict__ q, const float* __restrict__ k,
    const float* __restrict__ v, const int* __restrict__ mask,
    float* __restrict__ attn, float* __restrict__ ao)
{
    __shared__ __align__(16) float Qs[64][68];   // [d][row]
    __shared__ __align__(16) float Ks[64][68];   // [d][key]
    __shared__ __align__(16) float Vs[64][68];   // [key][d]
    __shared__ __align__(16) float Ps[64][68];   // [key][row]
    __shared__ float linv[64];
    __shared__ float msf[64];

    const int tid = threadIdx.x;
    const int qt = blockIdx.x, h = blockIdx.y, b = blockIdx.z;
    const int bh = b * Hn + h;
    const int lr = tid >> 2;            // stage row 0..63
    const int cg = (tid & 3) * 16;      // stage col group
    const int r0 = (tid >> 4) * 4;      // micro rows
    const int c0 = (tid & 15) * 4;      // micro cols (keys) / dims in PV

    // stage Q tile transposed: Qs[d][row]
    {
        const float* qp = q + ((size_t)bh * Sn + qt * 64 + lr) * Dn + cg;
        #pragma unroll
        for (int u = 0; u < 4; ++u) {
            float4 t = *(const float4*)(qp + 4 * u);
            Qs[cg + 4*u + 0][lr] = t.x; Qs[cg + 4*u + 1][lr] = t.y;
            Qs[cg + 4*u + 2][lr] = t.z; Qs[cg + 4*u + 3][lr] = t.w;
        }
    }

    float lsum[4] = {0.f, 0.f, 0.f, 0.f};

    // ---- pass A: softmax denominators ----
    for (int k0 = 0; k0 < Sn; k0 += 64) {
        __syncthreads();
        const float* kp = k + ((size_t)bh * Sn + k0 + lr) * Dn + cg;
        #pragma unroll
        for (int u = 0; u < 4; ++u) {
            float4 t = *(const float4*)(kp + 4 * u);
            Ks[cg + 4*u + 0][lr] = t.x; Ks[cg + 4*u + 1][lr] = t.y;
            Ks[cg + 4*u + 2][lr] = t.z; Ks[cg + 4*u + 3][lr] = t.w;
        }
        if (tid < 64) msf[tid] = (float)mask[b * Sn + k0 + tid];
        __syncthreads();

        float s[4][4] = {{0.f}};
        #pragma unroll 8
        for (int d = 0; d < 64; ++d) {
            float4 qa = *(const float4*)&Qs[d][r0];
            float4 kb = *(const float4*)&Ks[d][c0];
            const float a[4] = {qa.x, qa.y, qa.z, qa.w};
            const float bbq[4] = {kb.x, kb.y, kb.z, kb.w};
            #pragma unroll
            for (int i = 0; i < 4; ++i)
                #pragma unroll
                for (int j = 0; j < 4; ++j)
                    s[i][j] += a[i] * bbq[j];
        }
        const float mv[4] = {msf[c0], msf[c0+1], msf[c0+2], msf[c0+3]};
        #pragma unroll
        for (int i = 0; i < 4; ++i)
            #pragma unroll
            for (int j = 0; j < 4; ++j)
                lsum[i] += __expf(s[i][j] * 0.125f) * mv[j];
    }

    // reduce lsum across the 16 threads sharing each row group
    #pragma unroll
    for (int i = 0; i < 4; ++i) {
        #pragma unroll
        for (int m = 1; m < 16; m <<= 1)
            lsum[i] += __shfl_xor(lsum[i], m, 64);
    }
    if ((tid & 15) == 0) {
        #pragma unroll
        for (int i = 0; i < 4; ++i)
            linv[r0 + i] = lsum[i] > 0.f ? 1.f / lsum[i] : 0.f;
    }
    __syncthreads();
    const float li[4] = {linv[r0], linv[r0+1], linv[r0+2], linv[r0+3]};

    float o[4][4] = {{0.f}};

    // ---- pass B: weights out + P@V ----
    for (int k0 = 0; k0 < Sn; k0 += 64) {
        __syncthreads();
        {
            const float* kp = k + ((size_t)bh * Sn + k0 + lr) * Dn + cg;
            const float* vp = v + ((size_t)bh * Sn + k0 + lr) * Dn + cg;
            #pragma unroll
            for (int u = 0; u < 4; ++u) {
                float4 t = *(const float4*)(kp + 4 * u);
                Ks[cg + 4*u + 0][lr] = t.x; Ks[cg + 4*u + 1][lr] = t.y;
                Ks[cg + 4*u + 2][lr] = t.z; Ks[cg + 4*u + 3][lr] = t.w;
                *(float4*)&Vs[lr][cg + 4 * u] = *(const float4*)(vp + 4 * u);
            }
            if (tid < 64) msf[tid] = (float)mask[b * Sn + k0 + tid];
        }
        __syncthreads();

        float s[4][4] = {{0.f}};
        #pragma unroll 8
        for (int d = 0; d < 64; ++d) {
            float4 qa = *(const float4*)&Qs[d][r0];
            float4 kb = *(const float4*)&Ks[d][c0];
            const float a[4] = {qa.x, qa.y, qa.z, qa.w};
            const float bbq[4] = {kb.x, kb.y, kb.z, kb.w};
            #pragma unroll
            for (int i = 0; i < 4; ++i)
                #pragma unroll
                for (int j = 0; j < 4; ++j)
                    s[i][j] += a[i] * bbq[j];
        }
        const float mv[4] = {msf[c0], msf[c0+1], msf[c0+2], msf[c0+3]};
        #pragma unroll
        for (int i = 0; i < 4; ++i) {
            float p[4];
            #pragma unroll
            for (int j = 0; j < 4; ++j) {
                p[j] = __expf(s[i][j] * 0.125f) * mv[j] * li[i];
                Ps[c0 + j][r0 + i] = p[j];
            }
            float* dst = attn + ((size_t)bh * Sn + qt * 64 + r0 + i) * Sn + k0 + c0;
            *(float4*)dst = make_float4(p[0], p[1], p[2], p[3]);
        }
        __syncthreads();

        #pragma unroll 8
        for (int c = 0; c < 64; ++c) {
            float4 pa = *(const float4*)&Ps[c][r0];
            float4 vv = *(const float4*)&Vs[c][c0];
            const float a[4] = {pa.x, pa.y, pa.z, pa.w};
            const float bbv[4] = {vv.x, vv.y, vv.z, vv.w};
            #pragma unroll
            for (int i = 0; i < 4; ++i)
                #pragma unroll
                for (int j = 0; j < 4; ++j)
                    o[i][j] += a[i] * bbv[j];
        }
    }

    // write attention output in [B,S,W] layout
    #pragma unroll
    for (int i = 0; i < 4; ++i) {
        float* dst = ao + ((size_t)b * Sn + qt * 64 + r0 + i) * Wn + h * Dn + c0;
        *(float4*)dst = make_float4(o[i][0], o[i][1], o[i][2], o[i][3]);
    }
}

// ---------------------------------------------------------------------------
// Kernel 3: output projection.  out[M=4096, N=768] = AO @ o_w^T + o_b
// Same 128x128x8 structure as kernel 1.
// ---------------------------------------------------------------------------
__global__ __launch_bounds__(256) void oproj_kernel(
    const float* __restrict__ ao, const float* __restrict__ ow,
    const float* __restrict__ ob, float* __restrict__ out)
{
    __shared__ __align__(16) float As[8][132];
    __shared__ __align__(16) float Bs[8][132];
    const int tid = threadIdx.x;
    const int m0 = blockIdx.x * 128;
    const int n0 = blockIdx.y * 128;

    const int lr = tid >> 1;
    const int lc = (tid & 1) * 4;
    const int tr = (tid >> 4) * 8;
    const int tc = (tid & 15) * 8;

    float acc[8][8];
    #pragma unroll
    for (int i = 0; i < 8; ++i)
        #pragma unroll
        for (int j = 0; j < 8; ++j) acc[i][j] = 0.f;

    for (int k0 = 0; k0 < Wn; k0 += 8) {
        float4 av = *(const float4*)(ao + (size_t)(m0 + lr) * Wn + k0 + lc);
        float4 bv = *(const float4*)(ow + (size_t)(n0 + lr) * En + k0 + lc);
        __syncthreads();
        As[lc + 0][lr] = av.x; As[lc + 1][lr] = av.y;
        As[lc + 2][lr] = av.z; As[lc + 3][lr] = av.w;
        Bs[lc + 0][lr] = bv.x; Bs[lc + 1][lr] = bv.y;
        Bs[lc + 2][lr] = bv.z; Bs[lc + 3][lr] = bv.w;
        __syncthreads();
        #pragma unroll
        for (int kk = 0; kk < 8; ++kk) {
            float a[8], bb[8];
            *(float4*)&a[0]  = *(const float4*)&As[kk][tr];
            *(float4*)&a[4]  = *(const float4*)&As[kk][tr + 4];
            *(float4*)&bb[0] = *(const float4*)&Bs[kk][tc];
            *(float4*)&bb[4] = *(const float4*)&Bs[kk][tc + 4];
            #pragma unroll
            for (int i = 0; i < 8; ++i)
                #pragma unroll
                for (int j = 0; j < 8; ++j)
                    acc[i][j] += a[i] * bb[j];
        }
    }

    float bias[8];
    #pragma unroll
    for (int j = 0; j < 8; ++j) bias[j] = ob[n0 + tc + j];

    #pragma unroll
    for (int i = 0; i < 8; ++i) {
        float* dst = out + (size_t)(m0 + tr + i) * Wn + n0 + tc;
        float4 v0 = make_float4(acc[i][0] + bias[0], acc[i][1] + bias[1],
                                acc[i][2] + bias[2], acc[i][3] + bias[3]);
        float4 v1 = make_float4(acc[i][4] + bias[4], acc[i][5] + bias[5],
                                acc[i][6] + bias[6], acc[i][7] + bias[7]);
        *(float4*)(dst)     = v0;
        *(float4*)(dst + 4) = v1;
    }
}

// ---------------------------------------------------------------------------
extern "C" void kernel_launch(void* const* d_in, const int* in_sizes, int n_in,
                              void* d_out, int out_size, void* d_ws, size_t ws_size,
                              hipStream_t stream) {
    const float* x    = (const float*)d_in[0];
    const int*   mask = (const int*)  d_in[1];
    const float* qw = (const float*)d_in[2];
    const float* qb = (const float*)d_in[3];
    const float* kw = (const float*)d_in[4];
    const float* kb = (const float*)d_in[5];
    const float* vw = (const float*)d_in[6];
    const float* vb = (const float*)d_in[7];
    const float* ow = (const float*)d_in[8];
    const float* ob = (const float*)d_in[9];
    // d_in[10] = width (768 for this problem's setup_inputs; grid is static)

    float* out  = (float*)d_out;                       // [4096, 768]
    float* attn = out + (size_t)Bn * Sn * Wn;          // [B,H,S,S]

    const size_t elems = (size_t)Bn * Sn * Wn;         // 3,145,728
    float* q_ws  = (float*)d_ws;
    float* k_ws  = q_ws + elems;
    float* v_ws  = k_ws + elems;
    float* ao_ws = v_ws + elems;

    qkv_kernel<<<dim3(32, 18), 256, 0, stream>>>(x, qw, qb, kw, kb, vw, vb,
                                                 q_ws, k_ws, v_ws);
    attn_kernel<<<dim3(16, Hn, Bn), 256, 0, stream>>>(q_ws, k_ws, v_ws, mask,
                                                      attn, ao_ws);
    oproj_kernel<<<dim3(32, 6), 256, 0, stream>>>(ao_ws, ow, ob, out);
}

// Round 2
// 451.274 us; speedup vs baseline: 1.7998x; 1.7998x over previous
//
#include <hip/hip_runtime.h>

#define Bn 4
#define Sn 1024
#define En 1024
#define Wn 768
#define Hn 12
#define Dn 64

typedef __attribute__((ext_vector_type(8))) short short8;
typedef __attribute__((ext_vector_type(4))) short short4v;
typedef __attribute__((ext_vector_type(4))) float floatx4;

#define MFMA16(A, B, C) __builtin_amdgcn_mfma_f32_16x16x32_bf16(A, B, C, 0, 0, 0)

__device__ __forceinline__ unsigned short f2bf_rn(float f) {
    unsigned int u = __float_as_uint(f);
    unsigned int r = u + 0x7fffu + ((u >> 16) & 1u);
    return (unsigned short)(r >> 16);
}
__device__ __forceinline__ float bf2f(unsigned short h) {
    return __uint_as_float(((unsigned int)h) << 16);
}

__device__ __forceinline__ void gload_lds16(const unsigned short* g, unsigned short* l) {
    __builtin_amdgcn_global_load_lds(
        (const __attribute__((address_space(1))) void*)g,
        (__attribute__((address_space(3))) void*)l, 16, 0, 0);
}

// ---------------------------------------------------------------------------
// Split fp32 -> bf16 hi/lo.  x: [4096][1024] -> xh/xl [4096][768]
// ---------------------------------------------------------------------------
__global__ __launch_bounds__(256) void split_x_kernel(
    const float* __restrict__ x, unsigned short* __restrict__ xh,
    unsigned short* __restrict__ xl)
{
    int e = (blockIdx.x * 256 + threadIdx.x) * 4;   // over 4096*768
    int row = e / Wn, col = e - row * Wn;
    float4 v = *(const float4*)(x + (size_t)row * En + col);
    float f[4] = {v.x, v.y, v.z, v.w};
    short4v h, l;
    #pragma unroll
    for (int i = 0; i < 4; ++i) {
        unsigned short hh = f2bf_rn(f[i]);
        h[i] = (short)hh;
        l[i] = (short)f2bf_rn(f[i] - bf2f(hh));
    }
    *(short4v*)(xh + e) = h;
    *(short4v*)(xl + e) = l;
}

// w: [1024][1024], slice [768][768] -> dh/dl (768 cols, caller offsets rows)
__global__ __launch_bounds__(256) void split_w_kernel(
    const float* __restrict__ w, unsigned short* __restrict__ dh,
    unsigned short* __restrict__ dl)
{
    int e = (blockIdx.x * 256 + threadIdx.x) * 4;   // over 768*768
    int row = e / Wn, col = e - row * Wn;
    float4 v = *(const float4*)(w + (size_t)row * En + col);
    float f[4] = {v.x, v.y, v.z, v.w};
    short4v h, l;
    #pragma unroll
    for (int i = 0; i < 4; ++i) {
        unsigned short hh = f2bf_rn(f[i]);
        h[i] = (short)hh;
        l[i] = (short)f2bf_rn(f[i] - bf2f(hh));
    }
    *(short4v*)(dh + e) = h;
    *(short4v*)(dl + e) = l;
}

__global__ __launch_bounds__(256) void concat_bias_kernel(
    const float* __restrict__ qb, const float* __restrict__ kb,
    const float* __restrict__ vb, float* __restrict__ bq)
{
    int t = blockIdx.x * 256 + threadIdx.x;
    if (t < Wn) bq[t] = qb[t];
    else if (t < 2 * Wn) bq[t] = kb[t - Wn];
    else if (t < 3 * Wn) bq[t] = vb[t - 2 * Wn];
}

// ---------------------------------------------------------------------------
// QKV GEMM: C[4096, 2304] = X @ Wqkv^T + b  via bf16x3 MFMA.
// 128x128 tile, BK=32, 4 waves (2x2 of 64x64).  A/B staged with
// global_load_lds (16B), XOR-swizzled chunks so frag ds_read_b128 is 2-way.
// Epilogue: q/k -> hi/lo bf16 [B,H,S,D]; v -> bf16 [B,H,D,S] (transposed).
// ---------------------------------------------------------------------------
__global__ __launch_bounds__(256) void qkv_mfma_kernel(
    const unsigned short* __restrict__ xh, const unsigned short* __restrict__ xl,
    const unsigned short* __restrict__ wh, const unsigned short* __restrict__ wl,
    const float* __restrict__ bq,
    unsigned short* __restrict__ qh_o, unsigned short* __restrict__ ql_o,
    unsigned short* __restrict__ kh_o, unsigned short* __restrict__ kl_o,
    unsigned short* __restrict__ vt_o)
{
    __shared__ __align__(16) unsigned short Ah[128 * 32];
    __shared__ __align__(16) unsigned short Al[128 * 32];
    __shared__ __align__(16) unsigned short Bh[128 * 32];
    __shared__ __align__(16) unsigned short Bl[128 * 32];

    const int tid = threadIdx.x;
    const int wave = tid >> 6, lane = tid & 63;
    const int quad = lane >> 4, l16 = lane & 15;
    const int m0 = blockIdx.x * 128, n0 = blockIdx.y * 128;
    const int wm = wave >> 1, wn = wave & 1;

    floatx4 acc[4][4] = {};

    const unsigned short* gsrc = (wave == 0) ? xh : (wave == 1) ? xl
                               : (wave == 2) ? wh : wl;
    unsigned short* ldst = (wave == 0) ? Ah : (wave == 1) ? Al
                         : (wave == 2) ? Bh : Bl;
    const int base_row = (wave < 2) ? m0 : n0;
    const int r_in = lane >> 2;                   // 0..15
    const int cs = (lane & 3) ^ (r_in & 3);       // swizzled global chunk

    for (int k0 = 0; k0 < Wn; k0 += 32) {
        #pragma unroll
        for (int i = 0; i < 8; ++i) {
            int r = i * 16 + r_in;
            const unsigned short* gp =
                gsrc + (size_t)(base_row + r) * Wn + k0 + cs * 8;
            gload_lds16(gp, ldst + i * 512);
        }
        __syncthreads();

        short8 afh[4], afl[4], bfh[4], bfl[4];
        #pragma unroll
        for (int t = 0; t < 4; ++t) {
            int mr = wm * 64 + t * 16 + l16;
            int ca = quad ^ (mr & 3);
            afh[t] = *(const short8*)(Ah + mr * 32 + ca * 8);
            afl[t] = *(const short8*)(Al + mr * 32 + ca * 8);
            int nr = wn * 64 + t * 16 + l16;
            int cb = quad ^ (nr & 3);
            bfh[t] = *(const short8*)(Bh + nr * 32 + cb * 8);
            bfl[t] = *(const short8*)(Bl + nr * 32 + cb * 8);
        }
        #pragma unroll
        for (int mt = 0; mt < 4; ++mt)
            #pragma unroll
            for (int nt = 0; nt < 4; ++nt) {
                acc[mt][nt] = MFMA16(afh[mt], bfh[nt], acc[mt][nt]);
                acc[mt][nt] = MFMA16(afh[mt], bfl[nt], acc[mt][nt]);
                acc[mt][nt] = MFMA16(afl[mt], bfh[nt], acc[mt][nt]);
            }
        __syncthreads();
    }

    // epilogue
    const int which = n0 / Wn;                 // 0=q 1=k 2=v (uniform per block)
    const int b = m0 >> 10;
    #pragma unroll
    for (int nt = 0; nt < 4; ++nt) {
        const int ng = n0 + wn * 64 + nt * 16 + l16;
        const float bias = bq[ng];
        const int f = ng - which * Wn;
        const int h = f >> 6, d = f & 63;
        #pragma unroll
        for (int mt = 0; mt < 4; ++mt) {
            const int mbase = m0 + wm * 64 + mt * 16 + quad * 4;
            const int s0 = mbase & (Sn - 1);
            if (which < 2) {
                unsigned short* oh = which ? kh_o : qh_o;
                unsigned short* ol = which ? kl_o : ql_o;
                size_t idx = (((size_t)(b * Hn + h)) * Sn + s0) * Dn + d;
                #pragma unroll
                for (int r = 0; r < 4; ++r) {
                    float vv = acc[mt][nt][r] + bias;
                    unsigned short hh = f2bf_rn(vv);
                    oh[idx + (size_t)r * Dn] = hh;
                    ol[idx + (size_t)r * Dn] = f2bf_rn(vv - bf2f(hh));
                }
            } else {
                size_t idx = (((size_t)(b * Hn + h)) * Dn + d) * Sn + s0;
                short4v pk;
                #pragma unroll
                for (int r = 0; r < 4; ++r)
                    pk[r] = (short)f2bf_rn(acc[mt][nt][r] + bias);
                *(short4v*)(vt_o + idx) = pk;
            }
        }
    }
}

// ---------------------------------------------------------------------------
// Attention: block = (qt, h, b), 64 q-rows, 4 waves x 16 rows.
// Pass A: denominators via split-bf16 MFMA QK^T.  Pass B: recompute scores,
// write fp32 weights, PV via bf16 MFMA (P through LDS transpose).
// ---------------------------------------------------------------------------
__global__ __launch_bounds__(256) void attn_mfma_kernel(
    const unsigned short* __restrict__ qh, const unsigned short* __restrict__ ql,
    const unsigned short* __restrict__ kh, const unsigned short* __restrict__ kl,
    const unsigned short* __restrict__ vt, const int* __restrict__ mask,
    float* __restrict__ attn, unsigned short* __restrict__ aoh,
    unsigned short* __restrict__ aol)
{
    __shared__ __align__(16) unsigned short Kh[64 * 72];
    __shared__ __align__(16) unsigned short Kl[64 * 72];
    __shared__ __align__(16) unsigned short Vs[64 * 72];
    __shared__ __align__(16) unsigned short Ps[4][16 * 72];
    __shared__ float msk[64];

    const int tid = threadIdx.x;
    const int wave = tid >> 6, lane = tid & 63;
    const int quad = lane >> 4, l16 = lane & 15;
    const int qt = blockIdx.x, h = blockIdx.y, b = blockIdx.z;
    const int bh = b * Hn + h;
    const size_t kvbase = (size_t)bh * Sn * Dn;

    // Q fragments in registers (A-operand: m=l16, k=quad*8+j)
    short8 qfh[2], qfl[2];
    {
        const int s = qt * 64 + wave * 16 + l16;
        const size_t off = kvbase + (size_t)s * Dn + quad * 8;
        qfh[0] = *(const short8*)(qh + off);
        qfh[1] = *(const short8*)(qh + off + 32);
        qfl[0] = *(const short8*)(ql + off);
        qfl[1] = *(const short8*)(ql + off + 32);
    }

    const int sr = tid >> 2;        // staging row 0..63
    const int sc = tid & 3;         // staging chunk

    float lsum[4] = {0.f, 0.f, 0.f, 0.f};

    // ---- pass A ----
    for (int kt = 0; kt < 16; ++kt) {
        __syncthreads();
        {
            const size_t g = kvbase + (size_t)(kt * 64 + sr) * Dn + sc * 16;
            *(short8*)&Kh[sr * 72 + sc * 16]     = *(const short8*)(kh + g);
            *(short8*)&Kh[sr * 72 + sc * 16 + 8] = *(const short8*)(kh + g + 8);
            *(short8*)&Kl[sr * 72 + sc * 16]     = *(const short8*)(kl + g);
            *(short8*)&Kl[sr * 72 + sc * 16 + 8] = *(const short8*)(kl + g + 8);
            if (tid < 64) msk[tid] = (float)mask[b * Sn + kt * 64 + tid];
        }
        __syncthreads();
        #pragma unroll
        for (int ct = 0; ct < 4; ++ct) {
            floatx4 acc = {0.f, 0.f, 0.f, 0.f};
            const int key = ct * 16 + l16;
            #pragma unroll
            for (int ks = 0; ks < 2; ++ks) {
                short8 b8h = *(const short8*)&Kh[key * 72 + ks * 32 + quad * 8];
                short8 b8l = *(const short8*)&Kl[key * 72 + ks * 32 + quad * 8];
                acc = MFMA16(qfh[ks], b8h, acc);
                acc = MFMA16(qfh[ks], b8l, acc);
                acc = MFMA16(qfl[ks], b8h, acc);
            }
            const float mv = msk[key];
            #pragma unroll
            for (int r = 0; r < 4; ++r)
                lsum[r] += __expf(acc[r] * 0.125f) * mv;
        }
    }

    // reduce across the 16 lanes of each quad group; invert
    #pragma unroll
    for (int r = 0; r < 4; ++r) {
        float v = lsum[r];
        v += __shfl_xor(v, 1, 64);
        v += __shfl_xor(v, 2, 64);
        v += __shfl_xor(v, 4, 64);
        v += __shfl_xor(v, 8, 64);
        lsum[r] = (v > 0.f) ? 1.f / v : 0.f;
    }

    floatx4 oacc[4] = {};
    const size_t vbase = (size_t)bh * Dn * Sn;

    // ---- pass B ----
    for (int kt = 0; kt < 16; ++kt) {
        __syncthreads();
        {
            const size_t g = kvbase + (size_t)(kt * 64 + sr) * Dn + sc * 16;
            *(short8*)&Kh[sr * 72 + sc * 16]     = *(const short8*)(kh + g);
            *(short8*)&Kh[sr * 72 + sc * 16 + 8] = *(const short8*)(kh + g + 8);
            *(short8*)&Kl[sr * 72 + sc * 16]     = *(const short8*)(kl + g);
            *(short8*)&Kl[sr * 72 + sc * 16 + 8] = *(const short8*)(kl + g + 8);
            const size_t g2 = vbase + (size_t)sr * Sn + kt * 64 + sc * 16;
            *(short8*)&Vs[sr * 72 + sc * 16]     = *(const short8*)(vt + g2);
            *(short8*)&Vs[sr * 72 + sc * 16 + 8] = *(const short8*)(vt + g2 + 8);
            if (tid < 64) msk[tid] = (float)mask[b * Sn + kt * 64 + tid];
        }
        __syncthreads();

        #pragma unroll
        for (int ct = 0; ct < 4; ++ct) {
            floatx4 acc = {0.f, 0.f, 0.f, 0.f};
            const int key = ct * 16 + l16;
            #pragma unroll
            for (int ks = 0; ks < 2; ++ks) {
                short8 b8h = *(const short8*)&Kh[key * 72 + ks * 32 + quad * 8];
                short8 b8l = *(const short8*)&Kl[key * 72 + ks * 32 + quad * 8];
                acc = MFMA16(qfh[ks], b8h, acc);
                acc = MFMA16(qfh[ks], b8l, acc);
                acc = MFMA16(qfl[ks], b8h, acc);
            }
            const float mv = msk[key];
            const int row0 = qt * 64 + wave * 16 + quad * 4;
            const int key_g = kt * 64 + key;
            #pragma unroll
            for (int r = 0; r < 4; ++r) {
                float p = __expf(acc[r] * 0.125f) * mv * lsum[r];
                attn[((size_t)bh * Sn + row0 + r) * Sn + key_g] = p;
                Ps[wave][(quad * 4 + r) * 72 + key] = f2bf_rn(p);
            }
        }
        // PV: wave-local Ps (in-wave LDS ordering, no barrier needed)
        #pragma unroll
        for (int ks = 0; ks < 2; ++ks) {
            short8 pf = *(const short8*)&Ps[wave][l16 * 72 + ks * 32 + quad * 8];
            #pragma unroll
            for (int dt = 0; dt < 4; ++dt) {
                short8 vf = *(const short8*)&Vs[(dt * 16 + l16) * 72 + ks * 32 + quad * 8];
                oacc[dt] = MFMA16(pf, vf, oacc[dt]);
            }
        }
    }

    // epilogue: ao -> bf16 hi/lo [B,S,W]
    const int s0 = qt * 64 + wave * 16 + quad * 4;
    #pragma unroll
    for (int dt = 0; dt < 4; ++dt)
        #pragma unroll
        for (int r = 0; r < 4; ++r) {
            float v = oacc[dt][r];
            size_t idx = ((size_t)(b * Sn + s0 + r)) * Wn + h * Dn + dt * 16 + l16;
            unsigned short hh = f2bf_rn(v);
            aoh[idx] = hh;
            aol[idx] = f2bf_rn(v - bf2f(hh));
        }
}

// ---------------------------------------------------------------------------
// O projection: out[4096,768] = AO @ Wo^T + b, bf16x3 MFMA, fp32 out.
// ---------------------------------------------------------------------------
__global__ __launch_bounds__(256) void oproj_mfma_kernel(
    const unsigned short* __restrict__ aoh, const unsigned short* __restrict__ aol,
    const unsigned short* __restrict__ wh, const unsigned short* __restrict__ wl,
    const float* __restrict__ ob, float* __restrict__ out)
{
    __shared__ __align__(16) unsigned short Ah[128 * 32];
    __shared__ __align__(16) unsigned short Al[128 * 32];
    __shared__ __align__(16) unsigned short Bh[128 * 32];
    __shared__ __align__(16) unsigned short Bl[128 * 32];

    const int tid = threadIdx.x;
    const int wave = tid >> 6, lane = tid & 63;
    const int quad = lane >> 4, l16 = lane & 15;
    const int m0 = blockIdx.x * 128, n0 = blockIdx.y * 128;
    const int wm = wave >> 1, wn = wave & 1;

    floatx4 acc[4][4] = {};

    const unsigned short* gsrc = (wave == 0) ? aoh : (wave == 1) ? aol
                               : (wave == 2) ? wh : wl;
    unsigned short* ldst = (wave == 0) ? Ah : (wave == 1) ? Al
                         : (wave == 2) ? Bh : Bl;
    const int base_row = (wave < 2) ? m0 : n0;
    const int r_in = lane >> 2;
    const int cs = (lane & 3) ^ (r_in & 3);

    for (int k0 = 0; k0 < Wn; k0 += 32) {
        #pragma unroll
        for (int i = 0; i < 8; ++i) {
            int r = i * 16 + r_in;
            const unsigned short* gp =
                gsrc + (size_t)(base_row + r) * Wn + k0 + cs * 8;
            gload_lds16(gp, ldst + i * 512);
        }
        __syncthreads();

        short8 afh[4], afl[4], bfh[4], bfl[4];
        #pragma unroll
        for (int t = 0; t < 4; ++t) {
            int mr = wm * 64 + t * 16 + l16;
            int ca = quad ^ (mr & 3);
            afh[t] = *(const short8*)(Ah + mr * 32 + ca * 8);
            afl[t] = *(const short8*)(Al + mr * 32 + ca * 8);
            int nr = wn * 64 + t * 16 + l16;
            int cb = quad ^ (nr & 3);
            bfh[t] = *(const short8*)(Bh + nr * 32 + cb * 8);
            bfl[t] = *(const short8*)(Bl + nr * 32 + cb * 8);
        }
        #pragma unroll
        for (int mt = 0; mt < 4; ++mt)
            #pragma unroll
            for (int nt = 0; nt < 4; ++nt) {
                acc[mt][nt] = MFMA16(afh[mt], bfh[nt], acc[mt][nt]);
                acc[mt][nt] = MFMA16(afh[mt], bfl[nt], acc[mt][nt]);
                acc[mt][nt] = MFMA16(afl[mt], bfh[nt], acc[mt][nt]);
            }
        __syncthreads();
    }

    #pragma unroll
    for (int nt = 0; nt < 4; ++nt) {
        const int ng = n0 + wn * 64 + nt * 16 + l16;
        const float bias = ob[ng];
        #pragma unroll
        for (int mt = 0; mt < 4; ++mt) {
            const int m = m0 + wm * 64 + mt * 16 + quad * 4;
            #pragma unroll
            for (int r = 0; r < 4; ++r)
                out[(size_t)(m + r) * Wn + ng] = acc[mt][nt][r] + bias;
        }
    }
}

// ---------------------------------------------------------------------------
extern "C" void kernel_launch(void* const* d_in, const int* in_sizes, int n_in,
                              void* d_out, int out_size, void* d_ws, size_t ws_size,
                              hipStream_t stream) {
    const float* x    = (const float*)d_in[0];
    const int*   mask = (const int*)  d_in[1];
    const float* qw = (const float*)d_in[2];
    const float* qb = (const float*)d_in[3];
    const float* kw = (const float*)d_in[4];
    const float* kb = (const float*)d_in[5];
    const float* vw = (const float*)d_in[6];
    const float* vb = (const float*)d_in[7];
    const float* ow = (const float*)d_in[8];
    const float* ob = (const float*)d_in[9];
    // d_in[10] = width (768 in this problem; grid is static)

    float* out  = (float*)d_out;                       // [4096, 768]
    float* attn = out + (size_t)Bn * Sn * Wn;          // [B,H,S,S]

    const size_t XE  = (size_t)Bn * Sn * Wn;           // 3,145,728 elems
    const size_t QKE = (size_t)Bn * Hn * Sn * Dn;      // 3,145,728 elems
    char* w = (char*)d_ws;
    unsigned short* xh   = (unsigned short*)w;  w += XE * 2;     // also aoh later
    unsigned short* xl   = (unsigned short*)w;  w += XE * 2;     // also aol later
    unsigned short* wqh  = (unsigned short*)w;  w += (size_t)3 * Wn * Wn * 2;
    unsigned short* wql  = (unsigned short*)w;  w += (size_t)3 * Wn * Wn * 2;
    unsigned short* woh  = (unsigned short*)w;  w += (size_t)Wn * Wn * 2;
    unsigned short* wol  = (unsigned short*)w;  w += (size_t)Wn * Wn * 2;
    float*          bq   = (float*)w;           w += (size_t)3 * Wn * 4;
    unsigned short* qh_w = (unsigned short*)w;  w += QKE * 2;
    unsigned short* ql_w = (unsigned short*)w;  w += QKE * 2;
    unsigned short* kh_w = (unsigned short*)w;  w += QKE * 2;
    unsigned short* kl_w = (unsigned short*)w;  w += QKE * 2;
    unsigned short* vt_w = (unsigned short*)w;  w += QKE * 2;

    split_x_kernel<<<3072, 256, 0, stream>>>(x, xh, xl);
    split_w_kernel<<<576, 256, 0, stream>>>(qw, wqh, wql);
    split_w_kernel<<<576, 256, 0, stream>>>(kw, wqh + (size_t)Wn * Wn, wql + (size_t)Wn * Wn);
    split_w_kernel<<<576, 256, 0, stream>>>(vw, wqh + (size_t)2 * Wn * Wn, wql + (size_t)2 * Wn * Wn);
    split_w_kernel<<<576, 256, 0, stream>>>(ow, woh, wol);
    concat_bias_kernel<<<9, 256, 0, stream>>>(qb, kb, vb, bq);

    qkv_mfma_kernel<<<dim3(32, 18), 256, 0, stream>>>(
        xh, xl, wqh, wql, bq, qh_w, ql_w, kh_w, kl_w, vt_w);

    // ao reuses xh/xl (x fully consumed by qkv kernel; stream-ordered)
    attn_mfma_kernel<<<dim3(16, Hn, Bn), 256, 0, stream>>>(
        qh_w, ql_w, kh_w, kl_w, vt_w, mask, attn, xh, xl);

    oproj_mfma_kernel<<<dim3(32, 6), 256, 0, stream>>>(
        xh, xl, woh, wol, ob, out);
}